// Round 1
// baseline (182.276 us; speedup 1.0000x reference)
//
#include <hip/hip_runtime.h>
#include <math.h>

#define B_    32
#define H0    512
#define W0    512
#define C1    3        // conv1 out channels
#define Hh    255      // pooled height
#define Wh    255      // pooled width
#define KK_   9
#define TILE  16

// ---------------- Kernel A: conv1(3x3,pad1) + ReLU + maxpool(3x3,s2,VALID) ----------------
// grid: (ceil(Wh/16)=16, ceil(Hh/16)=16, B), block: (16,16)
__global__ __launch_bounds__(256) void conv_pool_kernel(
    const float* __restrict__ x,      // [B,1,512,512]
    const float* __restrict__ w,      // [3,1,3,3]
    const float* __restrict__ bias,   // [3]
    float* __restrict__ h)            // [B,3,255,255]
{
    __shared__ float sx[35][36];      // 35x35 input tile, padded stride
    const int b  = blockIdx.z;
    const int i0 = blockIdx.y * TILE;
    const int j0 = blockIdx.x * TILE;
    const int tx = threadIdx.x, ty = threadIdx.y;
    const int tid = ty * 16 + tx;

    const float* xb = x + (size_t)b * H0 * W0;
    // input rows 2*i0-1 .. 2*i0+33, cols 2*j0-1 .. 2*j0+33 (zero-padded)
    for (int t = tid; t < 35 * 35; t += 256) {
        int r = t / 35, c = t - r * 35;
        int gr = 2 * i0 - 1 + r;
        int gc = 2 * j0 - 1 + c;
        float v = 0.f;
        if (gr >= 0 && gr < H0 && gc >= 0 && gc < W0) v = xb[gr * W0 + gc];
        sx[r][c] = v;
    }
    __syncthreads();

    const int i = i0 + ty, j = j0 + tx;
    if (i >= Hh || j >= Wh) return;

    float w0[9], w1[9], w2[9];
#pragma unroll
    for (int t = 0; t < 9; ++t) { w0[t] = w[t]; w1[t] = w[9 + t]; w2[t] = w[18 + t]; }
    const float b0 = bias[0], b1 = bias[1], b2 = bias[2];

    float m0 = 0.f, m1 = 0.f, m2 = 0.f;   // relu >= 0, so 0 is a safe init for max-after-relu
#pragma unroll
    for (int pr = 0; pr < 3; ++pr) {
#pragma unroll
        for (int pc = 0; pc < 3; ++pc) {
            float s0 = b0, s1 = b1, s2 = b2;
#pragma unroll
            for (int ky = 0; ky < 3; ++ky) {
#pragma unroll
                for (int kx = 0; kx < 3; ++kx) {
                    float v = sx[2 * ty + pr + ky][2 * tx + pc + kx];
                    s0 = fmaf(w0[ky * 3 + kx], v, s0);
                    s1 = fmaf(w1[ky * 3 + kx], v, s1);
                    s2 = fmaf(w2[ky * 3 + kx], v, s2);
                }
            }
            m0 = fmaxf(m0, s0);
            m1 = fmaxf(m1, s1);
            m2 = fmaxf(m2, s2);
        }
    }
    const size_t hw = (size_t)Hh * Wh;
    const size_t o  = (size_t)b * 3 * hw + (size_t)i * Wh + j;
    h[o]          = m0;
    h[o + hw]     = m1;
    h[o + 2 * hw] = m2;
}

// ---------------- Kernel B: offset-conv + bilinear deform gather + mask + einsum ----------------
// grid: (Hh, B), block: 256 threads (one per output column; 255 active)
__global__ __launch_bounds__(256) void dcn_kernel(
    const float* __restrict__ h,       // [B,3,255,255]
    const float* __restrict__ off_w,   // [27,3,3,3]
    const float* __restrict__ off_b,   // [27]
    const float* __restrict__ dcn_w,   // [3,3,3,3] -> (o,c,k)
    const float* __restrict__ dcn_b,   // [3]
    float* __restrict__ out)           // [B,3,255,255]
{
    const int y = blockIdx.x;
    const int b = blockIdx.y;
    const int x = threadIdx.x;
    if (x >= Wh) return;

    const size_t hwsz = (size_t)Hh * Wh;
    const float* hb = h + (size_t)b * 3 * hwsz;

    // 3x3 zero-padded window of h around (y,x), all 3 channels
    float win[3][9];
#pragma unroll
    for (int c = 0; c < 3; ++c) {
        const float* hc = hb + c * hwsz;
#pragma unroll
        for (int ky = 0; ky < 3; ++ky) {
            const int yy = y - 1 + ky;
            const bool yok = (yy >= 0) && (yy < Hh);
#pragma unroll
            for (int kx = 0; kx < 3; ++kx) {
                const int xx = x - 1 + kx;
                float v = 0.f;
                if (yok && xx >= 0 && xx < Wh) v = hc[yy * Wh + xx];
                win[c][ky * 3 + kx] = v;
            }
        }
    }

    // 27-channel offset conv (weights are wave-uniform -> scalar loads)
    float om[27];
#pragma unroll
    for (int o = 0; o < 27; ++o) {
        float s = off_b[o];
#pragma unroll
        for (int c = 0; c < 3; ++c) {
#pragma unroll
            for (int t = 0; t < 9; ++t) {
                s = fmaf(off_w[(o * 3 + c) * 9 + t], win[c][t], s);
            }
        }
        om[o] = s;
    }

    float outv0 = dcn_b[0], outv1 = dcn_b[1], outv2 = dcn_b[2];

#pragma unroll
    for (int k = 0; k < KK_; ++k) {
        const float dy = om[k];
        const float dx = om[9 + k];
        const float msk = 1.f / (1.f + __expf(-om[18 + k]));

        const float py = (float)(y - 1 + k / 3) + dy;
        const float px = (float)(x - 1 + k % 3) + dx;

        const float y0f = floorf(py), x0f = floorf(px);
        const float ly = py - y0f, lx = px - x0f;
        const int y0 = (int)y0f, x0 = (int)x0f;

        const bool vy0 = (y0 >= 0) && (y0 <= Hh - 1);
        const bool vy1 = (y0 + 1 >= 0) && (y0 + 1 <= Hh - 1);
        const bool vx0 = (x0 >= 0) && (x0 <= Wh - 1);
        const bool vx1 = (x0 + 1 >= 0) && (x0 + 1 <= Wh - 1);

        const int yA = min(max(y0, 0), Hh - 1);
        const int yB = min(max(y0 + 1, 0), Hh - 1);
        const int xA = min(max(x0, 0), Wh - 1);
        const int xB = min(max(x0 + 1, 0), Wh - 1);

        const float w00 = (1.f - ly) * (1.f - lx) * ((vy0 && vx0) ? 1.f : 0.f);
        const float w01 = (1.f - ly) * lx         * ((vy0 && vx1) ? 1.f : 0.f);
        const float w10 = ly * (1.f - lx)         * ((vy1 && vx0) ? 1.f : 0.f);
        const float w11 = ly * lx                 * ((vy1 && vx1) ? 1.f : 0.f);

        const int iAA = yA * Wh + xA;
        const int iAB = yA * Wh + xB;
        const int iBA = yB * Wh + xA;
        const int iBB = yB * Wh + xB;

#pragma unroll
        for (int c = 0; c < 3; ++c) {
            const float* hc = hb + c * hwsz;
            float s = w00 * hc[iAA] + w01 * hc[iAB] + w10 * hc[iBA] + w11 * hc[iBB];
            const float sm = s * msk;
            outv0 = fmaf(dcn_w[(0 * 3 + c) * 9 + k], sm, outv0);
            outv1 = fmaf(dcn_w[(1 * 3 + c) * 9 + k], sm, outv1);
            outv2 = fmaf(dcn_w[(2 * 3 + c) * 9 + k], sm, outv2);
        }
    }

    const size_t o = (size_t)b * 3 * hwsz + (size_t)y * Wh + x;
    out[o]            = outv0;
    out[o + hwsz]     = outv1;
    out[o + 2 * hwsz] = outv2;
}

extern "C" void kernel_launch(void* const* d_in, const int* in_sizes, int n_in,
                              void* d_out, int out_size, void* d_ws, size_t ws_size,
                              hipStream_t stream) {
    const float* x       = (const float*)d_in[0];
    const float* conv1_w = (const float*)d_in[1];
    const float* conv1_b = (const float*)d_in[2];
    const float* off_w   = (const float*)d_in[3];
    const float* off_b   = (const float*)d_in[4];
    const float* dcn_w   = (const float*)d_in[5];
    const float* dcn_b   = (const float*)d_in[6];
    float* out = (float*)d_out;
    float* h   = (float*)d_ws;   // 32*3*255*255*4 = ~23.8 MiB scratch

    dim3 gA((Wh + TILE - 1) / TILE, (Hh + TILE - 1) / TILE, B_);
    conv_pool_kernel<<<gA, dim3(16, 16), 0, stream>>>(x, conv1_w, conv1_b, h);

    dcn_kernel<<<dim3(Hh, B_), 256, 0, stream>>>(h, off_w, off_b, dcn_w, dcn_b, out);
}

// Round 2
// 108.830 us; speedup vs baseline: 1.6749x; 1.6749x over previous
//
#include <hip/hip_runtime.h>
#include <math.h>

#define B_    32
#define H0    512
#define W0    512
#define Hh    255
#define Wh    255
#define TILE  16

typedef __attribute__((ext_vector_type(8))) short    bf16x8;
typedef __attribute__((ext_vector_type(4))) float    f32x4;
typedef __attribute__((ext_vector_type(4))) unsigned int u32x4;

// f32 -> bf16 bits, round-to-nearest-even
static __device__ __forceinline__ unsigned int f2bf(float f) {
    unsigned int u = __float_as_uint(f);
    return (u + 0x7FFFu + ((u >> 16) & 1u)) >> 16;
}

// ---------------- Kernel A: conv1(3x3,pad1)+ReLU+maxpool(3x3,s2) -> h interleaved [B][255][255][3]
__global__ __launch_bounds__(256) void conv_pool_kernel(
    const float* __restrict__ x,      // [B,1,512,512]
    const float* __restrict__ w,      // [3,1,3,3]
    const float* __restrict__ bias,   // [3]
    float* __restrict__ h)            // [B,255,255,3] interleaved
{
    __shared__ float sx[35][36];
    const int b  = blockIdx.z;
    const int i0 = blockIdx.y * TILE;
    const int j0 = blockIdx.x * TILE;
    const int tx = threadIdx.x, ty = threadIdx.y;
    const int tid = ty * 16 + tx;

    const float* xb = x + (size_t)b * H0 * W0;
    for (int t = tid; t < 35 * 35; t += 256) {
        int r = t / 35, c = t - r * 35;
        int gr = 2 * i0 - 1 + r;
        int gc = 2 * j0 - 1 + c;
        float v = 0.f;
        if (gr >= 0 && gr < H0 && gc >= 0 && gc < W0) v = xb[gr * W0 + gc];
        sx[r][c] = v;
    }
    __syncthreads();

    const int i = i0 + ty, j = j0 + tx;
    if (i >= Hh || j >= Wh) return;

    float w0[9], w1[9], w2[9];
#pragma unroll
    for (int t = 0; t < 9; ++t) { w0[t] = w[t]; w1[t] = w[9 + t]; w2[t] = w[18 + t]; }
    const float b0 = bias[0], b1 = bias[1], b2 = bias[2];

    float m0 = 0.f, m1 = 0.f, m2 = 0.f;
#pragma unroll
    for (int pr = 0; pr < 3; ++pr) {
#pragma unroll
        for (int pc = 0; pc < 3; ++pc) {
            float s0 = b0, s1 = b1, s2 = b2;
#pragma unroll
            for (int ky = 0; ky < 3; ++ky) {
#pragma unroll
                for (int kx = 0; kx < 3; ++kx) {
                    float v = sx[2 * ty + pr + ky][2 * tx + pc + kx];
                    s0 = fmaf(w0[ky * 3 + kx], v, s0);
                    s1 = fmaf(w1[ky * 3 + kx], v, s1);
                    s2 = fmaf(w2[ky * 3 + kx], v, s2);
                }
            }
            m0 = fmaxf(m0, s0);
            m1 = fmaxf(m1, s1);
            m2 = fmaxf(m2, s2);
        }
    }
    float* po = h + ((size_t)b * Hh * Wh + (size_t)i * Wh + j) * 3;
    po[0] = m0; po[1] = m1; po[2] = m2;
}

// ---------------- Kernel B: MFMA offset-conv + bilinear deform gather + mask + einsum
// grid: (Hh, B), block 256 (4 waves). Block = one output row.
__global__ __launch_bounds__(256, 5) void dcn_kernel(
    const float* __restrict__ h,       // [B,255,255,3] interleaved
    const float* __restrict__ off_w,   // [27,27] (=[27][3][3][3] flat)
    const float* __restrict__ off_b,   // [27]
    const float* __restrict__ dcn_w,   // [3,3,9]
    const float* __restrict__ dcn_b,   // [3]
    float* __restrict__ out)           // [B,3,255,255] planar
{
    // 31744B: bytes [0,16384) double as A im2col [kchunk4][px256][8]bf16,
    // bytes [16384,18432) as B [n32][k32]bf16; om_s overwrites after MFMA.
    __shared__ __align__(16) char smem[256 * 31 * 4];
    float (*om_s)[31] = (float (*)[31])smem;

    const int y   = blockIdx.x;
    const int b   = blockIdx.y;
    const int tid = threadIdx.x;
    const int x   = tid;

    const float* hb = h + (size_t)b * (Hh * Wh * 3);

    // ---- B matrix -> LDS (padded 32x32, bf16)
    {
        unsigned short* Bm = (unsigned short*)(smem + 16384);
        for (int idx = tid; idx < 1024; idx += 256) {
            int n = idx >> 5, k = idx & 31;
            float v = (n < 27 && k < 27) ? off_w[n * 27 + k] : 0.f;
            Bm[n * 32 + k] = (unsigned short)f2bf(v);
        }
    }

    // ---- im2col window (zero-padded conv semantics), k = c*9 + ky*3 + kx
    float win[27];
    {
        const int  xc  = min(x, Wh - 1);            // lane 255: safe garbage
        const int  xm  = max(xc - 1, 0);
        const int  xp  = min(xc + 1, Wh - 1);
        const bool xv0 = (x - 1 >= 0);
        const bool xv2 = (x + 1 < Wh);
#pragma unroll
        for (int ky = 0; ky < 3; ++ky) {
            const int yy = y - 1 + ky;
            if (yy >= 0 && yy < Hh) {               // uniform branch
                const float* pr = hb + (size_t)yy * Wh * 3;
                const float* p0 = pr + xm * 3;
                const float* p1 = pr + xc * 3;
                const float* p2 = pr + xp * 3;
#pragma unroll
                for (int c = 0; c < 3; ++c) {
                    win[c * 9 + ky * 3 + 0] = xv0 ? p0[c] : 0.f;
                    win[c * 9 + ky * 3 + 1] = p1[c];
                    win[c * 9 + ky * 3 + 2] = xv2 ? p2[c] : 0.f;
                }
            } else {
#pragma unroll
                for (int c = 0; c < 3; ++c) {
                    win[c * 9 + ky * 3 + 0] = 0.f;
                    win[c * 9 + ky * 3 + 1] = 0.f;
                    win[c * 9 + ky * 3 + 2] = 0.f;
                }
            }
        }
    }

    // ---- pack to bf16, write A row: layout [kchunk][px][8] so frag reads are contiguous
    {
        unsigned int au[16];
#pragma unroll
        for (int i = 0; i < 16; ++i) {
            unsigned int lo = (2 * i     < 27) ? f2bf(win[2 * i])     : 0u;
            unsigned int hi = (2 * i + 1 < 27) ? f2bf(win[2 * i + 1]) : 0u;
            au[i] = lo | (hi << 16);
        }
#pragma unroll
        for (int c4 = 0; c4 < 4; ++c4) {
            u32x4 v = { au[c4 * 4 + 0], au[c4 * 4 + 1], au[c4 * 4 + 2], au[c4 * 4 + 3] };
            *(u32x4*)(smem + (size_t)(c4 * 256 + tid) * 16) = v;
        }
    }
    __syncthreads();

    // ---- MFMA: om[256][27] = A[256][32] * B^T ; D layout col=lane&15,row=(lane>>4)*4+q
    {
        const int wave = tid >> 6, lane = tid & 63;
        const int lrow = lane & 15, lchunk = lane >> 4;
        const short* As = (const short*)smem;
        const short* Bs = (const short*)(smem + 16384);

        bf16x8 afr[4];
#pragma unroll
        for (int m = 0; m < 4; ++m)
            afr[m] = *(const bf16x8*)(As + ((size_t)lchunk * 256 + wave * 64 + m * 16 + lrow) * 8);
        bf16x8 bfr[2];
#pragma unroll
        for (int nt = 0; nt < 2; ++nt)
            bfr[nt] = *(const bf16x8*)(Bs + ((size_t)(nt * 16 + lrow) * 32 + lchunk * 8));

        f32x4 acc[4][2];
#pragma unroll
        for (int m = 0; m < 4; ++m)
#pragma unroll
            for (int nt = 0; nt < 2; ++nt) {
                f32x4 z = {0.f, 0.f, 0.f, 0.f};
                acc[m][nt] = __builtin_amdgcn_mfma_f32_16x16x32_bf16(afr[m], bfr[nt], z, 0, 0, 0);
            }
        __syncthreads();   // everyone done reading A/B before om overwrites

        const int n0 = lrow;
#pragma unroll
        for (int m = 0; m < 4; ++m)
#pragma unroll
            for (int nt = 0; nt < 2; ++nt) {
                const int n = nt * 16 + n0;
                if (n < 27) {
                    const int pxb = wave * 64 + m * 16 + lchunk * 4;
                    om_s[pxb + 0][n] = acc[m][nt][0];
                    om_s[pxb + 1][n] = acc[m][nt][1];
                    om_s[pxb + 2][n] = acc[m][nt][2];
                    om_s[pxb + 3][n] = acc[m][nt][3];
                }
            }
    }
    __syncthreads();

    // ---- gather + mask + einsum (per-pixel, om from LDS + bias)
    const float* omr = om_s[x];
    float outv0 = dcn_b[0], outv1 = dcn_b[1], outv2 = dcn_b[2];
    const float ybase = (float)(y - 1);
    const float xbase = (float)(x - 1);

#pragma unroll
    for (int k = 0; k < 9; ++k) {
        const float dy = omr[k]      + off_b[k];
        const float dx = omr[9 + k]  + off_b[9 + k];
        const float zm = omr[18 + k] + off_b[18 + k];
        const float msk = __builtin_amdgcn_rcpf(1.f + __expf(-zm));

        const float py = ybase + (float)(k / 3) + dy;
        const float px = xbase + (float)(k % 3) + dx;

        const float y0f = floorf(py), x0f = floorf(px);
        const float ly = py - y0f, lx = px - x0f;
        const int y0 = (int)y0f, x0 = (int)x0f;

        const bool vy0 = ((unsigned)y0       <= (unsigned)(Hh - 1));
        const bool vy1 = ((unsigned)(y0 + 1) <= (unsigned)(Hh - 1));
        const bool vx0 = ((unsigned)x0       <= (unsigned)(Wh - 1));
        const bool vx1 = ((unsigned)(x0 + 1) <= (unsigned)(Wh - 1));

        const int yA = min(max(y0, 0), Hh - 1);
        const int yB = min(max(y0 + 1, 0), Hh - 1);
        const int xA = min(max(x0, 0), Wh - 1);
        const int xB = min(max(x0 + 1, 0), Wh - 1);

        const float wy0 = vy0 ? (1.f - ly) : 0.f;
        const float wy1 = vy1 ? ly         : 0.f;
        const float wx0 = vx0 ? (1.f - lx) : 0.f;
        const float wx1 = vx1 ? lx         : 0.f;
        const float w00 = wy0 * wx0, w01 = wy0 * wx1;
        const float w10 = wy1 * wx0, w11 = wy1 * wx1;

        const float* pAA = hb + (size_t)(yA * Wh + xA) * 3;
        const float* pAB = hb + (size_t)(yA * Wh + xB) * 3;
        const float* pBA = hb + (size_t)(yB * Wh + xA) * 3;
        const float* pBB = hb + (size_t)(yB * Wh + xB) * 3;

#pragma unroll
        for (int c = 0; c < 3; ++c) {
            float s = w00 * pAA[c] + w01 * pAB[c] + w10 * pBA[c] + w11 * pBB[c];
            const float sm = s * msk;
            outv0 = fmaf(dcn_w[(0 * 3 + c) * 9 + k], sm, outv0);
            outv1 = fmaf(dcn_w[(1 * 3 + c) * 9 + k], sm, outv1);
            outv2 = fmaf(dcn_w[(2 * 3 + c) * 9 + k], sm, outv2);
        }
    }

    if (x < Wh) {
        const size_t hwsz = (size_t)Hh * Wh;
        const size_t o = (size_t)b * 3 * hwsz + (size_t)y * Wh + x;
        out[o]            = outv0;
        out[o + hwsz]     = outv1;
        out[o + 2 * hwsz] = outv2;
    }
}

extern "C" void kernel_launch(void* const* d_in, const int* in_sizes, int n_in,
                              void* d_out, int out_size, void* d_ws, size_t ws_size,
                              hipStream_t stream) {
    const float* x       = (const float*)d_in[0];
    const float* conv1_w = (const float*)d_in[1];
    const float* conv1_b = (const float*)d_in[2];
    const float* off_w   = (const float*)d_in[3];
    const float* off_b   = (const float*)d_in[4];
    const float* dcn_w   = (const float*)d_in[5];
    const float* dcn_b   = (const float*)d_in[6];
    float* out = (float*)d_out;
    float* h   = (float*)d_ws;   // 32*255*255*3*4 = ~23.8 MiB interleaved

    dim3 gA((Wh + TILE - 1) / TILE, (Hh + TILE - 1) / TILE, B_);
    conv_pool_kernel<<<gA, dim3(16, 16), 0, stream>>>(x, conv1_w, conv1_b, h);

    dcn_kernel<<<dim3(Hh, B_), 256, 0, stream>>>(h, off_w, off_b, dcn_w, dcn_b, out);
}

// Round 3
// 81.508 us; speedup vs baseline: 2.2363x; 1.3352x over previous
//
#include <hip/hip_runtime.h>
#include <math.h>

#define B_  32
#define H0  512
#define W0  512
#define Hh  255
#define Wh  255
#define HP  259   // padded: rows/cols 0,1 zero; 2..256 = data y=0..254; 257,258 zero

typedef __attribute__((ext_vector_type(8))) short    bf16x8;
typedef __attribute__((ext_vector_type(4))) float    f32x4;
typedef __attribute__((ext_vector_type(4))) unsigned int u32x4;

static __device__ __forceinline__ unsigned int f2bf(float f) {
    unsigned int u = __float_as_uint(f);
    return (u + 0x7FFFu + ((u >> 16) & 1u)) >> 16;
}
static __device__ __forceinline__ float bflo(unsigned int u) { return __uint_as_float(u << 16); }
static __device__ __forceinline__ float bfhi(unsigned int u) { return __uint_as_float(u & 0xFFFF0000u); }

// ---------------- Kernel A: conv1+ReLU+maxpool -> padded bf16x4 h ----------------
// grid (16,16,B), block (16,16). Two-stage: conv on 33x33 grid in LDS, then pool.
__global__ __launch_bounds__(256) void conv_pool_kernel(
    const float* __restrict__ x,      // [B,1,512,512]
    const float* __restrict__ w,      // [3,1,3,3]
    const float* __restrict__ bias,   // [3]
    uint2* __restrict__ hp)           // [B][259][259] of 4xbf16
{
    __shared__ float sx[35][36];
    __shared__ float sc[33 * 100];    // conv values [r][c*3+ch], row stride 100
    const int b  = blockIdx.z;
    const int i0 = blockIdx.y * 16;
    const int j0 = blockIdx.x * 16;
    const int tx = threadIdx.x, ty = threadIdx.y;
    const int tid = ty * 16 + tx;

    const float* xb = x + b * (H0 * W0);
    for (int t = tid; t < 35 * 35; t += 256) {
        int r = t / 35, c = t - r * 35;
        int gr = 2 * i0 - 1 + r;
        int gc = 2 * j0 - 1 + c;
        float v = 0.f;
        if ((unsigned)gr < (unsigned)H0 && (unsigned)gc < (unsigned)W0) v = xb[gr * W0 + gc];
        sx[r][c] = v;
    }
    __syncthreads();

    float w0[9], w1[9], w2[9];
#pragma unroll
    for (int t = 0; t < 9; ++t) { w0[t] = w[t]; w1[t] = w[9 + t]; w2[t] = w[18 + t]; }
    const float b0 = bias[0], b1 = bias[1], b2 = bias[2];

    // conv on the 33x33 grid (stride-1 points feeding the pool)
    for (int t = tid; t < 33 * 33; t += 256) {
        int r = t / 33, c = t - r * 33;
        float s0 = b0, s1 = b1, s2 = b2;
#pragma unroll
        for (int ky = 0; ky < 3; ++ky) {
#pragma unroll
            for (int kx = 0; kx < 3; ++kx) {
                float v = sx[r + ky][c + kx];
                s0 = fmaf(w0[ky * 3 + kx], v, s0);
                s1 = fmaf(w1[ky * 3 + kx], v, s1);
                s2 = fmaf(w2[ky * 3 + kx], v, s2);
            }
        }
        float* p = &sc[r * 100 + c * 3];
        p[0] = s0; p[1] = s1; p[2] = s2;
    }
    __syncthreads();

    const int i = i0 + ty, j = j0 + tx;
    if (i >= Hh || j >= Wh) return;

    float m0 = -1e30f, m1 = -1e30f, m2 = -1e30f;
#pragma unroll
    for (int pr = 0; pr < 3; ++pr) {
#pragma unroll
        for (int pc = 0; pc < 3; ++pc) {
            const float* p = &sc[(2 * ty + pr) * 100 + (2 * tx + pc) * 3];
            m0 = fmaxf(m0, p[0]);
            m1 = fmaxf(m1, p[1]);
            m2 = fmaxf(m2, p[2]);
        }
    }
    m0 = fmaxf(m0, 0.f); m1 = fmaxf(m1, 0.f); m2 = fmaxf(m2, 0.f);  // relu commutes with max

    uint2 v;
    v.x = f2bf(m0) | (f2bf(m1) << 16);
    v.y = f2bf(m2);                       // hi half zero
    hp[(b * HP + i + 2) * HP + (j + 2)] = v;
}

// ---------------- Kernel B: MFMA offset-conv + padded bilinear gather + einsum ----------------
// grid (Hh, B), block 256. LDS: A im2col [0,16384) + B [16384,18432); om[256][28] overlays all.
__global__ __launch_bounds__(256, 5) void dcn_kernel(
    const uint2* __restrict__ hp,      // [B][259][259] 4xbf16
    const float* __restrict__ off_w,   // [27,27]
    const float* __restrict__ off_b,   // [27]
    const float* __restrict__ dcn_w,   // [3,3,9]
    const float* __restrict__ dcn_b,   // [3]
    float* __restrict__ out)           // [B,3,255,255]
{
    __shared__ __align__(16) char smem[256 * 28 * 4];
    float* om_s = (float*)smem;

    const int y   = blockIdx.x;
    const int b   = blockIdx.y;
    const int tid = threadIdx.x;
    const int x   = tid;

    const uint2* hb = hp + b * (HP * HP);

    // ---- B matrix -> LDS (32x32 bf16, zero-padded)
    {
        unsigned short* Bm = (unsigned short*)(smem + 16384);
        for (int idx = tid; idx < 1024; idx += 256) {
            int n = idx >> 5, k = idx & 31;
            float v = (n < 27 && k < 27) ? off_w[n * 27 + k] : 0.f;
            Bm[n * 32 + k] = (unsigned short)f2bf(v);
        }
    }

    // ---- im2col row for pixel x: 9 positions from padded h (no edge logic needed)
    unsigned int L[9], Hv[9];
#pragma unroll
    for (int ky = 0; ky < 3; ++ky) {
        const unsigned int rbase = (unsigned int)(y + 1 + ky) * HP + (unsigned int)(x + 1);
#pragma unroll
        for (int kx = 0; kx < 3; ++kx) {
            uint2 v = hb[rbase + kx];
            L[ky * 3 + kx]  = v.x;   // c0 | c1<<16
            Hv[ky * 3 + kx] = v.y;   // c2 | 0
        }
    }

    // ---- assemble A row (k = c*9 + p) as 16 u32 of bf16 pairs
    {
        unsigned int T[16];
        T[0]  = (L[0] & 0xFFFFu) | (L[1] << 16);
        T[1]  = (L[2] & 0xFFFFu) | (L[3] << 16);
        T[2]  = (L[4] & 0xFFFFu) | (L[5] << 16);
        T[3]  = (L[6] & 0xFFFFu) | (L[7] << 16);
        T[4]  = (L[8] & 0xFFFFu) | (L[0] & 0xFFFF0000u);
        T[5]  = (L[1] >> 16) | (L[2] & 0xFFFF0000u);
        T[6]  = (L[3] >> 16) | (L[4] & 0xFFFF0000u);
        T[7]  = (L[5] >> 16) | (L[6] & 0xFFFF0000u);
        T[8]  = (L[7] >> 16) | (L[8] & 0xFFFF0000u);
        T[9]  = (Hv[0] & 0xFFFFu) | (Hv[1] << 16);
        T[10] = (Hv[2] & 0xFFFFu) | (Hv[3] << 16);
        T[11] = (Hv[4] & 0xFFFFu) | (Hv[5] << 16);
        T[12] = (Hv[6] & 0xFFFFu) | (Hv[7] << 16);
        T[13] = (Hv[8] & 0xFFFFu);
        T[14] = 0u;
        T[15] = 0u;
#pragma unroll
        for (int c4 = 0; c4 < 4; ++c4) {
            u32x4 v = { T[c4 * 4 + 0], T[c4 * 4 + 1], T[c4 * 4 + 2], T[c4 * 4 + 3] };
            *(u32x4*)(smem + (c4 * 256 + tid) * 16) = v;
        }
    }
    __syncthreads();

    // ---- MFMA: om[256][27] = A[256][32] x off_w^T
    {
        const int wave = tid >> 6, lane = tid & 63;
        const int lrow = lane & 15, lchunk = lane >> 4;
        const short* As = (const short*)smem;
        const short* Bs = (const short*)(smem + 16384);

        bf16x8 afr[4];
#pragma unroll
        for (int m = 0; m < 4; ++m)
            afr[m] = *(const bf16x8*)(As + (lchunk * 256 + wave * 64 + m * 16 + lrow) * 8);
        bf16x8 bfr[2];
#pragma unroll
        for (int nt = 0; nt < 2; ++nt)
            bfr[nt] = *(const bf16x8*)(Bs + ((nt * 16 + lrow) * 32 + lchunk * 8));

        f32x4 acc[4][2];
#pragma unroll
        for (int m = 0; m < 4; ++m)
#pragma unroll
            for (int nt = 0; nt < 2; ++nt) {
                f32x4 z = {0.f, 0.f, 0.f, 0.f};
                acc[m][nt] = __builtin_amdgcn_mfma_f32_16x16x32_bf16(afr[m], bfr[nt], z, 0, 0, 0);
            }
        __syncthreads();   // A/B reads done before om overlays

#pragma unroll
        for (int m = 0; m < 4; ++m)
#pragma unroll
            for (int nt = 0; nt < 2; ++nt) {
                const int n = nt * 16 + lrow;
                if (n < 27) {
                    const int pxb = wave * 64 + m * 16 + lchunk * 4;
                    om_s[(pxb + 0) * 28 + n] = acc[m][nt][0];
                    om_s[(pxb + 1) * 28 + n] = acc[m][nt][1];
                    om_s[(pxb + 2) * 28 + n] = acc[m][nt][2];
                    om_s[(pxb + 3) * 28 + n] = acc[m][nt][3];
                }
            }
    }
    __syncthreads();

    // ---- gather + mask + einsum
    f32x4 o4[7];
    {
        const f32x4* omv = (const f32x4*)(om_s + x * 28);
#pragma unroll
        for (int j = 0; j < 7; ++j) o4[j] = omv[j];
    }

    float outv0 = dcn_b[0], outv1 = dcn_b[1], outv2 = dcn_b[2];
    const float yf = (float)y, xf = (float)x;

#pragma unroll
    for (int k = 0; k < 9; ++k) {
        const float dy  = o4[k >> 2][k & 3]               + off_b[k];
        const float dxx = o4[(k + 9) >> 2][(k + 9) & 3]   + off_b[9 + k];
        const float zm  = o4[(k + 18) >> 2][(k + 18) & 3] + off_b[18 + k];
        const float msk = __builtin_amdgcn_rcpf(1.f + __expf(-zm));

        const float py = yf + (float)(k / 3 - 1) + dy;
        const float px = xf + (float)(k % 3 - 1) + dxx;

        const float y0f = floorf(py), x0f = floorf(px);
        const float ly = py - y0f, lx = px - x0f;
        int iy = (int)y0f, ix = (int)x0f;
        iy = min(max(iy, -2), 255);          // out-of-range corners land on stored zeros
        ix = min(max(ix, -2), 255);

        const unsigned int idx = (unsigned int)(iy + 2) * HP + (unsigned int)(ix + 2);
        const uint2 aAA = hb[idx];
        const uint2 aAB = hb[idx + 1];
        const uint2 aBA = hb[idx + HP];
        const uint2 aBB = hb[idx + HP + 1];

        const float my1 = ly * msk;
        const float my0 = msk - my1;          // (1-ly)*msk
        const float lx1 = 1.f - lx;
        const float w00 = my0 * lx1, w01 = my0 * lx;
        const float w10 = my1 * lx1, w11 = my1 * lx;

        const float s0 = w00 * bflo(aAA.x) + w01 * bflo(aAB.x) + w10 * bflo(aBA.x) + w11 * bflo(aBB.x);
        const float s1 = w00 * bfhi(aAA.x) + w01 * bfhi(aAB.x) + w10 * bfhi(aBA.x) + w11 * bfhi(aBB.x);
        const float s2 = w00 * bflo(aAA.y) + w01 * bflo(aAB.y) + w10 * bflo(aBA.y) + w11 * bflo(aBB.y);

        outv0 = fmaf(dcn_w[0 * 27 + 0 * 9 + k], s0, outv0);
        outv0 = fmaf(dcn_w[0 * 27 + 1 * 9 + k], s1, outv0);
        outv0 = fmaf(dcn_w[0 * 27 + 2 * 9 + k], s2, outv0);
        outv1 = fmaf(dcn_w[1 * 27 + 0 * 9 + k], s0, outv1);
        outv1 = fmaf(dcn_w[1 * 27 + 1 * 9 + k], s1, outv1);
        outv1 = fmaf(dcn_w[1 * 27 + 2 * 9 + k], s2, outv1);
        outv2 = fmaf(dcn_w[2 * 27 + 0 * 9 + k], s0, outv2);
        outv2 = fmaf(dcn_w[2 * 27 + 1 * 9 + k], s1, outv2);
        outv2 = fmaf(dcn_w[2 * 27 + 2 * 9 + k], s2, outv2);
    }

    if (x < Wh) {
        const int hwsz = Hh * Wh;
        const int o = (b * 3) * hwsz + y * Wh + x;
        out[o]            = outv0;
        out[o + hwsz]     = outv1;
        out[o + 2 * hwsz] = outv2;
    }
}

extern "C" void kernel_launch(void* const* d_in, const int* in_sizes, int n_in,
                              void* d_out, int out_size, void* d_ws, size_t ws_size,
                              hipStream_t stream) {
    const float* x       = (const float*)d_in[0];
    const float* conv1_w = (const float*)d_in[1];
    const float* conv1_b = (const float*)d_in[2];
    const float* off_w   = (const float*)d_in[3];
    const float* off_b   = (const float*)d_in[4];
    const float* dcn_w   = (const float*)d_in[5];
    const float* dcn_b   = (const float*)d_in[6];
    float* out = (float*)d_out;
    uint2* hp  = (uint2*)d_ws;    // 32*259*259*8 B = 17.2 MiB

    hipMemsetAsync(d_ws, 0, (size_t)B_ * HP * HP * sizeof(uint2), stream);

    conv_pool_kernel<<<dim3(16, 16, B_), dim3(16, 16), 0, stream>>>(x, conv1_w, conv1_b, hp);
    dcn_kernel<<<dim3(Hh, B_), 256, 0, stream>>>(hp, off_w, off_b, dcn_w, dcn_b, out);
}

// Round 6
// 71.669 us; speedup vs baseline: 2.5433x; 1.1373x over previous
//
#include <hip/hip_runtime.h>
#include <math.h>

#define B_  32
#define H0  512
#define W0  512
#define Hh  255
#define Wh  255
#define HP  259   // padded: rows/cols 0,1 zero; 2..256 = data y=0..254; 257,258 zero

typedef __attribute__((ext_vector_type(8))) short    bf16x8;
typedef __attribute__((ext_vector_type(4))) float    f32x4;
typedef __attribute__((ext_vector_type(4))) unsigned int u32x4;

static __device__ __forceinline__ unsigned int f2bf(float f) {
    unsigned int u = __float_as_uint(f);
    return (u + 0x7FFFu + ((u >> 16) & 1u)) >> 16;
}
static __device__ __forceinline__ float bflo(unsigned int u) { return __uint_as_float(u << 16); }
static __device__ __forceinline__ float bfhi(unsigned int u) { return __uint_as_float(u & 0xFFFF0000u); }

// ---------------- Kernel A: conv1+ReLU+maxpool -> padded bf16x4 h; ring blocks zero the pad ----------------
// grid (16,17,B): blockIdx.y==16 zeroes the pad ring; else 16x16 output tile.
__global__ __launch_bounds__(256) void conv_pool_kernel(
    const float* __restrict__ x,      // [B,1,512,512]
    const float* __restrict__ w,      // [3,1,3,3]
    const float* __restrict__ bias,   // [3]
    uint2* __restrict__ hp)           // [B][259][259] of 4xbf16
{
    const int b = blockIdx.z;
    const int tx = threadIdx.x, ty = threadIdx.y;
    const int tid = ty * 16 + tx;

    if (blockIdx.y == 16) {           // ---- pad-ring zeroing (16 blocks/image) ----
        uint2* hpb = hp + b * (HP * HP);
        const int gid = blockIdx.x * 256 + tid;
        if (gid < 2072) {
            int r, c;
            if (gid < 1036) {                      // row strips 0,1,257,258
                int rr = gid / 259; c = gid - rr * 259;
                r = rr + (rr >= 2 ? 255 : 0);
            } else {                               // col strips 0,1,257,258
                int u = gid - 1036;
                int cc = u / 259; r = u - cc * 259;
                c = cc + (cc >= 2 ? 255 : 0);
            }
            hpb[r * HP + c] = make_uint2(0u, 0u);
        }
        return;
    }

    __shared__ float sx[35][36];
    __shared__ float sc[33 * 100];    // conv values [r][c*3+ch]
    const int i0 = blockIdx.y * 16;
    const int j0 = blockIdx.x * 16;

    const float* xb = x + b * (H0 * W0);
    for (int t = tid; t < 35 * 35; t += 256) {
        int r = t / 35, c = t - r * 35;
        int gr = 2 * i0 - 1 + r;
        int gc = 2 * j0 - 1 + c;
        float v = 0.f;
        if ((unsigned)gr < (unsigned)H0 && (unsigned)gc < (unsigned)W0) v = xb[gr * W0 + gc];
        sx[r][c] = v;
    }
    __syncthreads();

    float w0[9], w1[9], w2[9];
#pragma unroll
    for (int t = 0; t < 9; ++t) { w0[t] = w[t]; w1[t] = w[9 + t]; w2[t] = w[18 + t]; }
    const float b0 = bias[0], b1 = bias[1], b2 = bias[2];

    for (int t = tid; t < 33 * 33; t += 256) {
        int r = t / 33, c = t - r * 33;
        float s0 = b0, s1 = b1, s2 = b2;
#pragma unroll
        for (int ky = 0; ky < 3; ++ky) {
#pragma unroll
            for (int kx = 0; kx < 3; ++kx) {
                float v = sx[r + ky][c + kx];
                s0 = fmaf(w0[ky * 3 + kx], v, s0);
                s1 = fmaf(w1[ky * 3 + kx], v, s1);
                s2 = fmaf(w2[ky * 3 + kx], v, s2);
            }
        }
        float* p = &sc[r * 100 + c * 3];
        p[0] = s0; p[1] = s1; p[2] = s2;
    }
    __syncthreads();

    const int i = i0 + ty, j = j0 + tx;
    if (i >= Hh || j >= Wh) return;

    const float* r0 = &sc[(2 * ty + 0) * 100 + (2 * tx) * 3];
    const float* r1 = &sc[(2 * ty + 1) * 100 + (2 * tx) * 3];
    const float* r2 = &sc[(2 * ty + 2) * 100 + (2 * tx) * 3];
#define MAX3_(a, bq, cq) fmaxf(fmaxf((a), (bq)), (cq))
    float m0 = MAX3_(MAX3_(r0[0], r0[3], r0[6]), MAX3_(r1[0], r1[3], r1[6]), MAX3_(r2[0], r2[3], r2[6]));
    float m1 = MAX3_(MAX3_(r0[1], r0[4], r0[7]), MAX3_(r1[1], r1[4], r1[7]), MAX3_(r2[1], r2[4], r2[7]));
    float m2 = MAX3_(MAX3_(r0[2], r0[5], r0[8]), MAX3_(r1[2], r1[5], r1[8]), MAX3_(r2[2], r2[5], r2[8]));
    m0 = fmaxf(m0, 0.f); m1 = fmaxf(m1, 0.f); m2 = fmaxf(m2, 0.f);   // relu commutes with max

    uint2 v;
    v.x = f2bf(m0) | (f2bf(m1) << 16);
    v.y = f2bf(m2);
    hp[(b * HP + i + 2) * HP + (j + 2)] = v;
}

// ---------------- Kernel B: MFMA offset-conv(+bias col) + padded bilinear gather + einsum ----------------
// grid (Hh, B), block 256. LDS: A [0,16384) + B [16384,18432); om f32 [256][28] overlays (R3-proven path).
__global__ __launch_bounds__(256, 5) void dcn_kernel(
    const uint2* __restrict__ hp,      // [B][259][259] 4xbf16
    const float* __restrict__ off_w,   // [27,27]
    const float* __restrict__ off_b,   // [27]
    const float* __restrict__ dcn_w,   // [3,3,9]
    const float* __restrict__ dcn_b,   // [3]
    float* __restrict__ out)           // [B,3,255,255]
{
    __shared__ __align__(16) char smem[256 * 28 * 4];
    float* om_s = (float*)smem;

    const int y   = blockIdx.x;
    const int b   = blockIdx.y;
    const int tid = threadIdx.x;
    const int x   = tid;

    const uint2* hb = hp + b * (HP * HP);

    // ---- B matrix -> LDS (32x32 bf16): cols 0..26 = off_w, col 27 = off_b (bias), rest 0
    {
        unsigned short* Bm = (unsigned short*)(smem + 16384);
        for (int idx = tid; idx < 1024; idx += 256) {
            int n = idx >> 5, k = idx & 31;
            float v = 0.f;
            if (n < 27) { if (k < 27) v = off_w[n * 27 + k]; else if (k == 27) v = off_b[n]; }
            Bm[n * 32 + k] = (unsigned short)f2bf(v);
        }
    }

    // ---- im2col row for pixel x from padded h
    unsigned int L[9], Hv[9];
#pragma unroll
    for (int ky = 0; ky < 3; ++ky) {
        const unsigned int rbase = (unsigned int)(y + 1 + ky) * HP + (unsigned int)(x + 1);
#pragma unroll
        for (int kx = 0; kx < 3; ++kx) {
            uint2 v = hb[rbase + kx];
            L[ky * 3 + kx]  = v.x;
            Hv[ky * 3 + kx] = v.y;
        }
    }

    // ---- assemble A row (k=c*9+p; k=27 -> constant 1.0 bias column)
    {
        unsigned int T[16];
        T[0]  = (L[0] & 0xFFFFu) | (L[1] << 16);
        T[1]  = (L[2] & 0xFFFFu) | (L[3] << 16);
        T[2]  = (L[4] & 0xFFFFu) | (L[5] << 16);
        T[3]  = (L[6] & 0xFFFFu) | (L[7] << 16);
        T[4]  = (L[8] & 0xFFFFu) | (L[0] & 0xFFFF0000u);
        T[5]  = (L[1] >> 16) | (L[2] & 0xFFFF0000u);
        T[6]  = (L[3] >> 16) | (L[4] & 0xFFFF0000u);
        T[7]  = (L[5] >> 16) | (L[6] & 0xFFFF0000u);
        T[8]  = (L[7] >> 16) | (L[8] & 0xFFFF0000u);
        T[9]  = (Hv[0] & 0xFFFFu) | (Hv[1] << 16);
        T[10] = (Hv[2] & 0xFFFFu) | (Hv[3] << 16);
        T[11] = (Hv[4] & 0xFFFFu) | (Hv[5] << 16);
        T[12] = (Hv[6] & 0xFFFFu) | (Hv[7] << 16);
        T[13] = (Hv[8] & 0xFFFFu) | 0x3F800000u;   // bf16(1.0) in k=27 slot
        T[14] = 0u;
        T[15] = 0u;
#pragma unroll
        for (int c4 = 0; c4 < 4; ++c4) {
            u32x4 v = { T[c4 * 4 + 0], T[c4 * 4 + 1], T[c4 * 4 + 2], T[c4 * 4 + 3] };
            *(u32x4*)(smem + (c4 * 256 + tid) * 16) = v;
        }
    }
    __syncthreads();

    // ---- MFMA: om[256 px][27] = A[256][32] x B^T ; f32 epilogue (R3-proven)
    {
        const int wave = tid >> 6, lane = tid & 63;
        const int lrow = lane & 15, lchunk = lane >> 4;
        const short* As = (const short*)smem;
        const short* Bs = (const short*)(smem + 16384);

        bf16x8 afr[4];
#pragma unroll
        for (int m = 0; m < 4; ++m)
            afr[m] = *(const bf16x8*)(As + (lchunk * 256 + wave * 64 + m * 16 + lrow) * 8);
        bf16x8 bfr[2];
#pragma unroll
        for (int nt = 0; nt < 2; ++nt)
            bfr[nt] = *(const bf16x8*)(Bs + ((nt * 16 + lrow) * 32 + lchunk * 8));

        f32x4 acc[4][2];
#pragma unroll
        for (int m = 0; m < 4; ++m)
#pragma unroll
            for (int nt = 0; nt < 2; ++nt) {
                f32x4 z = {0.f, 0.f, 0.f, 0.f};
                acc[m][nt] = __builtin_amdgcn_mfma_f32_16x16x32_bf16(afr[m], bfr[nt], z, 0, 0, 0);
            }
        __syncthreads();   // A/B reads done before om overlays

#pragma unroll
        for (int m = 0; m < 4; ++m)
#pragma unroll
            for (int nt = 0; nt < 2; ++nt) {
                const int n = nt * 16 + lrow;
                if (n < 27) {
                    const int pxb = wave * 64 + m * 16 + lchunk * 4;
                    om_s[(pxb + 0) * 28 + n] = acc[m][nt][0];
                    om_s[(pxb + 1) * 28 + n] = acc[m][nt][1];
                    om_s[(pxb + 2) * 28 + n] = acc[m][nt][2];
                    om_s[(pxb + 3) * 28 + n] = acc[m][nt][3];
                }
            }
    }
    __syncthreads();

    // ---- gather + mask + einsum (om already includes off_b via bias column)
    f32x4 o4[7];
    {
        const f32x4* omv = (const f32x4*)(om_s + x * 28);
#pragma unroll
        for (int j = 0; j < 7; ++j) o4[j] = omv[j];
    }

    float outv0 = dcn_b[0], outv1 = dcn_b[1], outv2 = dcn_b[2];
    const float yf = (float)y, xf = (float)x;

#pragma unroll
    for (int k = 0; k < 9; ++k) {
        const float dy  = o4[k >> 2][k & 3];
        const float dxx = o4[(k + 9) >> 2][(k + 9) & 3];
        const float zm  = o4[(k + 18) >> 2][(k + 18) & 3];
        const float msk = __builtin_amdgcn_rcpf(1.f + __expf(-zm));

        const float py = yf + (float)(k / 3 - 1) + dy;
        const float px = xf + (float)(k % 3 - 1) + dxx;

        const float y0f = floorf(py), x0f = floorf(px);
        const float ly = py - y0f, lx = px - x0f;
        int iy = (int)y0f + 2, ix = (int)x0f + 2;
        iy = min(max(iy, 0), 257);           // out-of-range corners land on stored zeros
        ix = min(max(ix, 0), 257);

        const unsigned int idx = (unsigned int)iy * HP + (unsigned int)ix;
        u32x4 ua, ub;                         // {AA.x, AA.y, AB.x, AB.y}, {BA.., BB..}
        __builtin_memcpy(&ua, hb + idx, 16);
        __builtin_memcpy(&ub, hb + idx + HP, 16);

        const float my1 = ly * msk;
        const float my0 = msk - my1;
        const float lx1 = 1.f - lx;
        const float w00 = my0 * lx1, w01 = my0 * lx;
        const float w10 = my1 * lx1, w11 = my1 * lx;

        const float s0 = w00 * bflo(ua.x) + w01 * bflo(ua.z) + w10 * bflo(ub.x) + w11 * bflo(ub.z);
        const float s1 = w00 * bfhi(ua.x) + w01 * bfhi(ua.z) + w10 * bfhi(ub.x) + w11 * bfhi(ub.z);
        const float s2 = w00 * bflo(ua.y) + w01 * bflo(ua.w) + w10 * bflo(ub.y) + w11 * bflo(ub.w);

        outv0 = fmaf(dcn_w[0 * 27 + 0 * 9 + k], s0, outv0);
        outv0 = fmaf(dcn_w[0 * 27 + 1 * 9 + k], s1, outv0);
        outv0 = fmaf(dcn_w[0 * 27 + 2 * 9 + k], s2, outv0);
        outv1 = fmaf(dcn_w[1 * 27 + 0 * 9 + k], s0, outv1);
        outv1 = fmaf(dcn_w[1 * 27 + 1 * 9 + k], s1, outv1);
        outv1 = fmaf(dcn_w[1 * 27 + 2 * 9 + k], s2, outv1);
        outv2 = fmaf(dcn_w[2 * 27 + 0 * 9 + k], s0, outv2);
        outv2 = fmaf(dcn_w[2 * 27 + 1 * 9 + k], s1, outv2);
        outv2 = fmaf(dcn_w[2 * 27 + 2 * 9 + k], s2, outv2);
    }

    if (x < Wh) {
        const int hwsz = Hh * Wh;
        const int o = (b * 3) * hwsz + y * Wh + x;
        out[o]            = outv0;
        out[o + hwsz]     = outv1;
        out[o + 2 * hwsz] = outv2;
    }
}

extern "C" void kernel_launch(void* const* d_in, const int* in_sizes, int n_in,
                              void* d_out, int out_size, void* d_ws, size_t ws_size,
                              hipStream_t stream) {
    const float* x       = (const float*)d_in[0];
    const float* conv1_w = (const float*)d_in[1];
    const float* conv1_b = (const float*)d_in[2];
    const float* off_w   = (const float*)d_in[3];
    const float* off_b   = (const float*)d_in[4];
    const float* dcn_w   = (const float*)d_in[5];
    const float* dcn_b   = (const float*)d_in[6];
    float* out = (float*)d_out;
    uint2* hp  = (uint2*)d_ws;    // 32*259*259*8 B = 17.2 MiB

    conv_pool_kernel<<<dim3(16, 17, B_), dim3(16, 16), 0, stream>>>(x, conv1_w, conv1_b, hp);
    dcn_kernel<<<dim3(Hh, B_), 256, 0, stream>>>(hp, off_w, off_b, dcn_w, dcn_b, out);
}